// Round 12
// baseline (239.378 us; speedup 1.0000x reference)
//
#include <hip/hip_runtime.h>
#include <stdint.h>

typedef __attribute__((ext_vector_type(8))) __bf16 bf16x8;
typedef __attribute__((ext_vector_type(4))) __bf16 bf16x4;
typedef __attribute__((ext_vector_type(4))) float  f32x4;

#define DEV __device__ __forceinline__

DEV void gload16(const void* g, void* l) {
  __builtin_amdgcn_global_load_lds((const __attribute__((address_space(1))) uint32_t*)g,
                                   (__attribute__((address_space(3))) uint32_t*)l,
                                   16, 0, 0);
}

DEV f32x4 mfma16(bf16x8 a, bf16x8 b, f32x4 c) {
  return __builtin_amdgcn_mfma_f32_16x16x32_bf16(a, b, c, 0, 0, 0);
}

// ---------------- workspace layout (bytes) ----------------
#define XB_OFF   0UL            // 16384 x 1088 bf16 = 35,651,584 ; reused as S after k_gemm
#define S_OFF    0UL            // S: 4 batches x 2048 x 2048 bf16 = 33,554,432
#define Q_OFF    35651584UL     // 16384 x 512 bf16  = 16,777,216
#define K_OFF    52428800UL
#define V_OFF    69206016UL
#define VT_OFF   85983232UL     // [8][512][2048] bf16
#define WT_OFF   102760448UL    // 1536 x 1088 bf16 = 3,342,336
#define BIAS_OFF 106102784UL    // 1536 f32
#define GATE_OFF 106108928UL    // 16384 f32

// ============ 8-phase-style 256^2 GEMM core (512 thr, 8 waves 2Mx4N) ============
// Per K-tile (BK=64): 4 phases; phase q computes m-frags {2q,2q+1} x 4 n-frags x 2 kk
// = 16 MFMA. Staging of tile t+1 front-loaded into phases 0 (A) and 1 (B) of tile
// t's group -> the per-tile vmcnt(0) at the group boundary sits >=2 phases after
// the last issue (latency hidden; loads span barriers). Buffer parity t&1 makes
// stage writes and ds_reads provably disjoint; boundary = per-wave vmcnt(0) +
// s_barrier (all waves' loads landed before any read of the new tile).
template<int NT>
DEV void gemm256(const char* Ab, int sA, const char* Bb, int sB,
                 char* As, char* Bs, f32x4 (&acc)[8][4], int tid) {
  const int w = tid >> 6, lane = tid & 63;
  const int g = lane >> 4, l15 = lane & 15;
  const int wm = w >> 2, wn = w & 3;

  auto stage = [&](const char* Gb, int sG, char* Ls, int t) {
    const int k0 = t * 128;
    #pragma unroll
    for (int i = 0; i < 4; ++i) {
      const int L = i * 8192 + tid * 16;
      const int row = L >> 7, ch = (L >> 4) & 7, sch = ch ^ (row & 7);
      gload16(Gb + (size_t)row * sG + k0 + sch * 16, Ls + L);
    }
  };

  // prologue: tile 0 -> buffer 0
  stage(Ab, sA, As, 0);
  stage(Bb, sB, Bs, 0);
  asm volatile("s_waitcnt vmcnt(0)" ::: "memory");
  __builtin_amdgcn_s_barrier();

  #pragma unroll 1
  for (int t = 0; t < NT; ++t) {
    char* Ac = As + (t & 1) * 32768;
    char* Bc = Bs + (t & 1) * 32768;
    char* An = As + ((t & 1) ^ 1) * 32768;
    char* Bn = Bs + ((t & 1) ^ 1) * 32768;
    bf16x8 bF[4][2];
    #pragma unroll
    for (int q = 0; q < 4; ++q) {
      bf16x8 aF[2][2];
      if (q == 0) {
        #pragma unroll
        for (int n = 0; n < 4; ++n)
          #pragma unroll
          for (int kk = 0; kk < 2; ++kk) {
            const int row = wn * 64 + n * 16 + l15;
            const int ch = (kk * 4 + g) ^ (row & 7);
            bF[n][kk] = *(const bf16x8*)(Bc + row * 128 + ch * 16);
          }
      }
      #pragma unroll
      for (int i = 0; i < 2; ++i)
        #pragma unroll
        for (int kk = 0; kk < 2; ++kk) {
          const int row = wm * 128 + (q * 2 + i) * 16 + l15;
          const int ch = (kk * 4 + g) ^ (row & 7);
          aF[i][kk] = *(const bf16x8*)(Ac + row * 128 + ch * 16);
        }
      if (t + 1 < NT) {
        if (q == 0)      stage(Ab, sA, An, t + 1);
        else if (q == 1) stage(Bb, sB, Bn, t + 1);
      }
      __builtin_amdgcn_sched_barrier(0);
      __builtin_amdgcn_s_barrier();
      asm volatile("s_waitcnt lgkmcnt(0)" ::: "memory");
      __builtin_amdgcn_sched_barrier(0);
      __builtin_amdgcn_s_setprio(1);
      #pragma unroll
      for (int i = 0; i < 2; ++i)
        #pragma unroll
        for (int n = 0; n < 4; ++n)
          #pragma unroll
          for (int kk = 0; kk < 2; ++kk)
            acc[q * 2 + i][n] = mfma16(aF[i][kk], bF[n][kk], acc[q * 2 + i][n]);
      __builtin_amdgcn_s_setprio(0);
      __builtin_amdgcn_sched_barrier(0);
      if (q < 3) {
        __builtin_amdgcn_s_barrier();
      } else {
        asm volatile("s_waitcnt vmcnt(0)" ::: "memory");
        __builtin_amdgcn_s_barrier();
      }
    }
  }
}

// ============ kernel 1: xb (concat, bf16) + gate ============
__global__ __launch_bounds__(256) void k_xbgate(
    const float* __restrict__ tf, const float* __restrict__ env,
    const float* __restrict__ Wg, const float* __restrict__ bg,
    __bf16* __restrict__ xb, float* __restrict__ gate) {
  const int row = blockIdx.x;     // 0..16383
  const int t   = threadIdx.x;    // 0..255
  const int b   = row >> 11;
  const float4 v  = ((const float4*)(tf + (size_t)row * 1024))[t];
  const float4 wv = ((const float4*)Wg)[t];
  float dot = v.x * wv.x + v.y * wv.y + v.z * wv.z + v.w * wv.w;
  bf16x4 o; o.x = (__bf16)v.x; o.y = (__bf16)v.y; o.z = (__bf16)v.z; o.w = (__bf16)v.w;
  *(bf16x4*)(xb + (size_t)row * 1088 + t * 4) = o;
  if (t < 16) {
    const float4 e  = ((const float4*)(env + b * 64))[t];
    const float4 we = ((const float4*)Wg)[256 + t];
    dot += e.x * we.x + e.y * we.y + e.z * we.z + e.w * we.w;
    bf16x4 oe; oe.x = (__bf16)e.x; oe.y = (__bf16)e.y; oe.z = (__bf16)e.z; oe.w = (__bf16)e.w;
    *(bf16x4*)(xb + (size_t)row * 1088 + 1024 + t * 4) = oe;
  }
  #pragma unroll
  for (int m = 1; m < 64; m <<= 1) dot += __shfl_xor(dot, m, 64);
  __shared__ float red[4];
  if ((t & 63) == 0) red[t >> 6] = dot;
  __syncthreads();
  if (t == 0) {
    const float d = red[0] + red[1] + red[2] + red[3] + bg[0];
    gate[row] = 0.03125f / (1.0f + __expf(-d));   // sigmoid * 1/sqrt(1024)
  }
}

// ============ kernel 2: Wt[n][k] = W[k][n] (bf16) + bias ============
__global__ __launch_bounds__(256) void k_wt(
    const float* __restrict__ Wq, const float* __restrict__ Wk, const float* __restrict__ Wv,
    const float* __restrict__ bq, const float* __restrict__ bk, const float* __restrict__ bv,
    __bf16* __restrict__ Wt, float* __restrict__ biasc) {
  const int n = blockIdx.x;      // 0..1535
  const int t = threadIdx.x;
  const float* W; const float* bias; int col;
  if (n < 512)       { W = Wq; bias = bq; col = n; }
  else if (n < 1024) { W = Wk; bias = bk; col = n - 512; }
  else               { W = Wv; bias = bv; col = n - 1024; }
  for (int kk = t; kk < 1088; kk += 256)
    Wt[(size_t)n * 1088 + kk] = (__bf16)W[(size_t)kk * 512 + col];
  if (t == 0) biasc[n] = bias[col];
}

// ============ kernel 3: QKV GEMM  M=16384 N=1536 K=1088, 8-phase 256^2 ============
// grid 384 = 8 XCD x (8 bm x 6 bn): A-panel reused 6x within an XCD's L2.
__global__ __launch_bounds__(512, 2) void k_gemm(
    const __bf16* __restrict__ xb, const __bf16* __restrict__ Wt,
    const float* __restrict__ biasc, const float* __restrict__ gate,
    __bf16* __restrict__ q, __bf16* __restrict__ k, __bf16* __restrict__ v) {
  __shared__ alignas(16) __bf16 As[2][16384];   // 64 KB
  __shared__ alignas(16) __bf16 Bs[2][16384];   // 64 KB
  const int id = blockIdx.x;
  const int xcd = id & 7, local = id >> 3;
  const int bm = xcd * 8 + (local & 7);   // 0..63
  const int bn = local >> 3;              // 0..5
  const int tid = threadIdx.x, w = tid >> 6, lane = tid & 63;
  const int g = lane >> 4, l15 = lane & 15;
  const int wm = w >> 2, wn = w & 3;
  f32x4 acc[8][4] = {};
  const char* Ab = (const char*)(xb + (size_t)bm * 256 * 1088);
  const char* Bb = (const char*)(Wt + (size_t)bn * 256 * 1088);

  gemm256<17>(Ab, 2176, Bb, 2176, (char*)As, (char*)Bs, acc, tid);

  const int base = bn * 256 + wn * 64;      // global col base of this wave
  const int which = base >> 9;              // 0=q 1=k 2=v (uniform per wave)
  __bf16* outp = (which == 0) ? q : (which == 1) ? k : v;
  const int colbase = base - which * 512;
  #pragma unroll
  for (int mf = 0; mf < 8; ++mf) {
    #pragma unroll
    for (int r = 0; r < 4; ++r) {
      const int mrow = bm * 256 + wm * 128 + mf * 16 + g * 4 + r;
      const float gt = (which == 0) ? gate[mrow] : 1.0f;
      #pragma unroll
      for (int n = 0; n < 4; ++n) {
        const int ncol = colbase + n * 16 + l15;
        float val = acc[mf][n][r] + biasc[base + n * 16 + l15];
        if (which == 0) val *= gt;
        outp[(size_t)mrow * 512 + ncol] = (__bf16)val;
      }
    }
  }
}

// ============ kernel 4: v [16384][512] -> vT [8][512][2048] ============
__global__ __launch_bounds__(256) void k_vtr(const __bf16* __restrict__ v,
                                             __bf16* __restrict__ vT) {
  __shared__ __bf16 tile[64][72];
  const int st = blockIdx.x, dt = blockIdx.y, b = blockIdx.z;
  const int t = threadIdx.x;
  {
    const int sl = t >> 2, dl = (t & 3) * 16;
    const __bf16* src = v + ((size_t)(b * 2048 + st * 64 + sl)) * 512 + dt * 64 + dl;
    *(bf16x8*)&tile[sl][dl]     = *(const bf16x8*)src;
    *(bf16x8*)&tile[sl][dl + 8] = *(const bf16x8*)(src + 8);
  }
  __syncthreads();
  {
    const int dl = t >> 2, sl = (t & 3) * 16;
    bf16x8 w0, w1;
    #pragma unroll
    for (int j = 0; j < 8; ++j) { w0[j] = tile[sl + j][dl]; w1[j] = tile[sl + 8 + j][dl]; }
    __bf16* dst = vT + ((size_t)(b * 512 + dt * 64 + dl)) * 2048 + st * 64 + sl;
    *(bf16x8*)dst = w0;
    *(bf16x8*)(dst + 8) = w1;
  }
}

// ============ kernel 5: S = exp(Q @ K^T), 8-phase 256^2, 4-batch group ============
// grid 256 exact (1 block/CU): batch = (id&7)>>1 (2 XCDs per batch);
// mt-panel's nt-blocks share an XCD -> Q panel fetched ~once.
__global__ __launch_bounds__(512, 2) void k_sexp(
    const __bf16* __restrict__ q, const __bf16* __restrict__ kg,
    __bf16* __restrict__ S) {
  __shared__ alignas(16) __bf16 As[2][16384];
  __shared__ alignas(16) __bf16 Bs[2][16384];
  const int id = blockIdx.x;
  const int batch = (id & 7) >> 1;
  const int t = ((id >> 3) << 1) | (id & 1);   // 0..63
  const int mt = t & 7, nt = t >> 3;           // 0..7 each
  const int tid = threadIdx.x, w = tid >> 6, lane = tid & 63;
  const int g = lane >> 4, l15 = lane & 15;
  const int wm = w >> 2, wn = w & 3;
  f32x4 acc[8][4] = {};
  const char* Ab = (const char*)(q  + ((size_t)batch * 2048 + mt * 256) * 512);
  const char* Bb = (const char*)(kg + ((size_t)batch * 2048 + nt * 256) * 512);

  gemm256<8>(Ab, 1024, Bb, 1024, (char*)As, (char*)Bs, acc, tid);

  // epilogue: S = bf16(exp(acc))   (m = 0 softmax, validated R6-R11)
  __bf16* Srow = S + (size_t)batch * 2048 * 2048;
  #pragma unroll
  for (int mf = 0; mf < 8; ++mf) {
    #pragma unroll
    for (int r = 0; r < 4; ++r) {
      const int mrow = mt * 256 + wm * 128 + mf * 16 + g * 4 + r;
      #pragma unroll
      for (int n = 0; n < 4; ++n) {
        const int ncol = nt * 256 + wn * 64 + n * 16 + l15;
        Srow[(size_t)mrow * 2048 + ncol] = (__bf16)__expf(acc[mf][n][r]);
      }
    }
  }
}

// ============ kernel 6: out = (S @ vT-rows) / (S @ 1) for a 4-batch group ============
// BM=64 BN=256 BK=64; grid 256 exact; 4 waves 2x2 (32x128/wave). (unchanged, R11)
__global__ __launch_bounds__(256, 2) void k_pv(
    const __bf16* __restrict__ S, const __bf16* __restrict__ vT,
    float* __restrict__ out) {
  __shared__ alignas(16) __bf16 As[4096];     //  64 rows x 64 k = 8KB
  __shared__ alignas(16) __bf16 Bs[16384];    // 256 rows x 64 k = 32KB
  const int id = blockIdx.x;                  // 0..255
  const int low3 = id & 7, high = id >> 3;
  const int batch = low3 >> 1;                // 0..3
  const int nt = high & 1;                    // 0..1
  const int mt = ((high >> 1) << 1) | (low3 & 1);   // 0..31
  const int tid = threadIdx.x, w = tid >> 6, lane = tid & 63;
  const int g = lane >> 4, l15 = lane & 15;
  const int wm = w >> 1, wn = w & 1;
  f32x4 acc[2][8] = {};
  f32x4 l_acc[2] = {};
  bf16x8 ones;
  #pragma unroll
  for (int j = 0; j < 8; ++j) ones[j] = (__bf16)1.0f;

  const char* Ab = (const char*)(S  + ((size_t)batch * 2048 + mt * 64) * 2048);
  const char* Bb = (const char*)(vT + ((size_t)batch * 512 + nt * 256) * 2048);

  for (int kt = 0; kt < 32; ++kt) {
    const int k0b = kt * 128;
    #pragma unroll
    for (int i = 0; i < 2; ++i) {
      const int L = i * 4096 + tid * 16;
      const int row = L >> 7, ch = (L >> 4) & 7, sch = ch ^ (row & 7);
      gload16(Ab + (size_t)row * 4096 + k0b + sch * 16, (char*)As + L);
    }
    #pragma unroll
    for (int i = 0; i < 8; ++i) {
      const int L = i * 4096 + tid * 16;
      const int row = L >> 7, ch = (L >> 4) & 7, sch = ch ^ (row & 7);
      gload16(Bb + (size_t)row * 4096 + k0b + sch * 16, (char*)Bs + L);
    }
    __syncthreads();
    #pragma unroll
    for (int kk = 0; kk < 2; ++kk) {
      bf16x8 aF[2], bF[8];
      #pragma unroll
      for (int i = 0; i < 2; ++i) {
        const int rowa = wm * 32 + i * 16 + l15;
        const int cha = (kk * 4 + g) ^ (rowa & 7);
        aF[i] = *(const bf16x8*)((const char*)As + rowa * 128 + cha * 16);
      }
      #pragma unroll
      for (int j = 0; j < 8; ++j) {
        const int rowb = wn * 128 + j * 16 + l15;
        const int chb = (kk * 4 + g) ^ (rowb & 7);
        bF[j] = *(const bf16x8*)((const char*)Bs + rowb * 128 + chb * 16);
      }
      #pragma unroll
      for (int i = 0; i < 2; ++i) {
        #pragma unroll
        for (int j = 0; j < 8; ++j)
          acc[i][j] = mfma16(aF[i], bF[j], acc[i][j]);
        l_acc[i] = mfma16(aF[i], ones, l_acc[i]);
      }
    }
    __syncthreads();
  }

  #pragma unroll
  for (int i = 0; i < 2; ++i) {
    #pragma unroll
    for (int r = 0; r < 4; ++r) {
      const size_t mrow = (size_t)batch * 2048 + mt * 64 + wm * 32 + i * 16 + g * 4 + r;
      const float inv = 1.0f / l_acc[i][r];
      #pragma unroll
      for (int j = 0; j < 8; ++j) {
        const int ncol = nt * 256 + wn * 128 + j * 16 + l15;
        out[mrow * 512 + ncol] = acc[i][j][r] * inv;
      }
    }
  }
}

// ============ launcher ============
extern "C" void kernel_launch(void* const* d_in, const int* in_sizes, int n_in,
                              void* d_out, int out_size, void* d_ws, size_t ws_size,
                              hipStream_t stream) {
  const float* tf  = (const float*)d_in[0];
  const float* env = (const float*)d_in[1];
  const float* Wq  = (const float*)d_in[2];
  const float* bq  = (const float*)d_in[3];
  const float* Wk  = (const float*)d_in[4];
  const float* bk  = (const float*)d_in[5];
  const float* Wv  = (const float*)d_in[6];
  const float* bv  = (const float*)d_in[7];
  const float* Wg  = (const float*)d_in[8];
  const float* bg  = (const float*)d_in[9];
  float* out = (float*)d_out;
  char* ws = (char*)d_ws;

  __bf16* xb   = (__bf16*)(ws + XB_OFF);
  __bf16* Sbuf = (__bf16*)(ws + S_OFF);
  __bf16* qb   = (__bf16*)(ws + Q_OFF);
  __bf16* kb   = (__bf16*)(ws + K_OFF);
  __bf16* vb   = (__bf16*)(ws + V_OFF);
  __bf16* vT   = (__bf16*)(ws + VT_OFF);
  __bf16* Wt   = (__bf16*)(ws + WT_OFF);
  float* biasc = (float*)(ws + BIAS_OFF);
  float* gate  = (float*)(ws + GATE_OFF);

  k_xbgate<<<dim3(16384), dim3(256), 0, stream>>>(tf, env, Wg, bg, xb, gate);
  k_wt<<<dim3(1536), dim3(256), 0, stream>>>(Wq, Wk, Wv, bq, bk, bv, Wt, biasc);
  k_gemm<<<dim3(384), dim3(512), 0, stream>>>(xb, Wt, biasc, gate, qb, kb, vb);
  k_vtr<<<dim3(32, 8, 8), dim3(256), 0, stream>>>(vb, vT);

  // attention as two GEMMs per 4-batch group; S reuses the dead xb region
  const size_t hb = 4UL * 2048 * 512;     // q/k elements per group
  const size_t hv = 4UL * 512 * 2048;     // vT elements per group
  const size_t ho = 4UL * 2048 * 512;     // out elements per group
  k_sexp<<<dim3(256), dim3(512), 0, stream>>>(qb, kb, Sbuf);
  k_pv  <<<dim3(256), dim3(256), 0, stream>>>(Sbuf, vT, out);
  k_sexp<<<dim3(256), dim3(512), 0, stream>>>(qb + hb, kb + hb, Sbuf);
  k_pv  <<<dim3(256), dim3(256), 0, stream>>>(Sbuf, vT + hv, out + ho);
}

// Round 13
// 179.499 us; speedup vs baseline: 1.3336x; 1.3336x over previous
//
#include <hip/hip_runtime.h>
#include <stdint.h>

typedef __attribute__((ext_vector_type(8))) __bf16 bf16x8;
typedef __attribute__((ext_vector_type(4))) __bf16 bf16x4;
typedef __attribute__((ext_vector_type(4))) float  f32x4;

#define DEV __device__ __forceinline__

DEV void gload16(const void* g, void* l) {
  __builtin_amdgcn_global_load_lds((const __attribute__((address_space(1))) uint32_t*)g,
                                   (__attribute__((address_space(3))) uint32_t*)l,
                                   16, 0, 0);
}

DEV f32x4 mfma16(bf16x8 a, bf16x8 b, f32x4 c) {
  return __builtin_amdgcn_mfma_f32_16x16x32_bf16(a, b, c, 0, 0, 0);
}

// ---------------- workspace layout (bytes) ----------------
#define XB_OFF   0UL            // 16384 x 1088 bf16 = 35,651,584 ; reused as S (group mode)
#define S_OFF    0UL            // S (4-batch group): 33,554,432
#define Q_OFF    35651584UL     // 16384 x 512 bf16  = 16,777,216
#define K_OFF    52428800UL
#define V_OFF    69206016UL
#define VT_OFF   85983232UL     // [8][512][2048] bf16
#define WT_OFF   102760448UL    // 1536 x 1088 bf16 = 3,342,336
#define BIAS_OFF 106102784UL    // 1536 f32
#define GATE_OFF 106108928UL    // 16384 f32
#define S8_OFF   106174464UL    // S (all 8 batches): 67,108,864 -> needs ws >= 173,283,328

// ============ kernel 1: xb (concat, bf16) + gate ============
__global__ __launch_bounds__(256) void k_xbgate(
    const float* __restrict__ tf, const float* __restrict__ env,
    const float* __restrict__ Wg, const float* __restrict__ bg,
    __bf16* __restrict__ xb, float* __restrict__ gate) {
  const int row = blockIdx.x;     // 0..16383
  const int t   = threadIdx.x;    // 0..255
  const int b   = row >> 11;
  const float4 v  = ((const float4*)(tf + (size_t)row * 1024))[t];
  const float4 wv = ((const float4*)Wg)[t];
  float dot = v.x * wv.x + v.y * wv.y + v.z * wv.z + v.w * wv.w;
  bf16x4 o; o.x = (__bf16)v.x; o.y = (__bf16)v.y; o.z = (__bf16)v.z; o.w = (__bf16)v.w;
  *(bf16x4*)(xb + (size_t)row * 1088 + t * 4) = o;
  if (t < 16) {
    const float4 e  = ((const float4*)(env + b * 64))[t];
    const float4 we = ((const float4*)Wg)[256 + t];
    dot += e.x * we.x + e.y * we.y + e.z * we.z + e.w * we.w;
    bf16x4 oe; oe.x = (__bf16)e.x; oe.y = (__bf16)e.y; oe.z = (__bf16)e.z; oe.w = (__bf16)e.w;
    *(bf16x4*)(xb + (size_t)row * 1088 + 1024 + t * 4) = oe;
  }
  #pragma unroll
  for (int m = 1; m < 64; m <<= 1) dot += __shfl_xor(dot, m, 64);
  __shared__ float red[4];
  if ((t & 63) == 0) red[t >> 6] = dot;
  __syncthreads();
  if (t == 0) {
    const float d = red[0] + red[1] + red[2] + red[3] + bg[0];
    gate[row] = 0.03125f / (1.0f + __expf(-d));   // sigmoid * 1/sqrt(1024)
  }
}

// ============ kernel 2: Wt transpose via LDS tiles (coalesced both sides) ============
// grid (17, 8, 3): 64x64 f32 tile; read coalesced float4 rows, write bf16x4 rows of Wt.
__global__ __launch_bounds__(256) void k_wt(
    const float* __restrict__ Wq, const float* __restrict__ Wk, const float* __restrict__ Wv,
    const float* __restrict__ bq, const float* __restrict__ bk, const float* __restrict__ bv,
    __bf16* __restrict__ Wt, float* __restrict__ biasc) {
  __shared__ float tile[64][65];   // pad -> 2-way max on transposed read (free)
  const int kt = blockIdx.x;       // kk tile: 0..16
  const int ct = blockIdx.y;       // col tile: 0..7
  const int which = blockIdx.z;    // 0=q 1=k 2=v
  const float* W    = (which == 0) ? Wq : (which == 1) ? Wk : Wv;
  const float* bias = (which == 0) ? bq : (which == 1) ? bk : bv;
  const int t = threadIdx.x;
  const int k0 = kt * 64, c0 = ct * 64;
  #pragma unroll
  for (int j = 0; j < 4; ++j) {
    const int rr = (t >> 4) + j * 16;
    const float4 v4 = *(const float4*)(W + (size_t)(k0 + rr) * 512 + c0 + (t & 15) * 4);
    tile[rr][(t & 15) * 4 + 0] = v4.x;
    tile[rr][(t & 15) * 4 + 1] = v4.y;
    tile[rr][(t & 15) * 4 + 2] = v4.z;
    tile[rr][(t & 15) * 4 + 3] = v4.w;
  }
  if (kt == 0 && t < 64) biasc[which * 512 + c0 + t] = bias[c0 + t];
  __syncthreads();
  #pragma unroll
  for (int j = 0; j < 4; ++j) {
    const int nl = (t >> 4) + j * 16;     // local col -> Wt row
    const int kl = (t & 15) * 4;          // local kk
    bf16x4 o;
    o.x = (__bf16)tile[kl + 0][nl];
    o.y = (__bf16)tile[kl + 1][nl];
    o.z = (__bf16)tile[kl + 2][nl];
    o.w = (__bf16)tile[kl + 3][nl];
    *(bf16x4*)(Wt + (size_t)(which * 512 + c0 + nl) * 1088 + k0 + kl) = o;
  }
}

// ============ kernel 3: QKV GEMM  M=16384 N=1536 K=1088 (R11 m97 structure) ============
__global__ __launch_bounds__(256, 3) void k_gemm(
    const __bf16* __restrict__ xb, const __bf16* __restrict__ Wt,
    const float* __restrict__ biasc, const float* __restrict__ gate,
    __bf16* __restrict__ q, __bf16* __restrict__ k, __bf16* __restrict__ v) {
  __shared__ alignas(16) __bf16 As[8192];
  __shared__ alignas(16) __bf16 Bs[8192];
  const int id = blockIdx.x;
  const int xcd = id & 7, local = id >> 3;
  const int bm = xcd * 16 + (local & 15);   // all bn-blocks of a bm share an XCD
  const int bn = local >> 4;
  const int tid = threadIdx.x, w = tid >> 6, lane = tid & 63;
  const int g = lane >> 4, l15 = lane & 15;
  const int wm = w >> 1, wn = w & 1;
  f32x4 acc[4][4] = {};
  const char* Ab = (const char*)(xb + (size_t)bm * 128 * 1088);
  const char* Bb = (const char*)(Wt + (size_t)bn * 128 * 1088);

  for (int kt = 0; kt < 17; ++kt) {
    const int k0b = kt * 128;
    #pragma unroll
    for (int i = 0; i < 4; ++i) {
      const int L = i * 4096 + w * 1024 + lane * 16;
      const int row = L >> 7;
      const int ch = (L >> 4) & 7;
      const int sch = ch ^ (row & 7);
      gload16(Ab + (size_t)row * 2176 + k0b + sch * 16, (char*)As + L);
      gload16(Bb + (size_t)row * 2176 + k0b + sch * 16, (char*)Bs + L);
    }
    __syncthreads();
    #pragma unroll
    for (int kk = 0; kk < 2; ++kk) {
      bf16x8 aF[4], bF[4];
      #pragma unroll
      for (int i = 0; i < 4; ++i) {
        const int rowa = wm * 64 + i * 16 + l15;
        const int cha = (kk * 4 + g) ^ (rowa & 7);
        aF[i] = *(const bf16x8*)((const char*)As + rowa * 128 + cha * 16);
        const int rowb = wn * 64 + i * 16 + l15;
        const int chb = (kk * 4 + g) ^ (rowb & 7);
        bF[i] = *(const bf16x8*)((const char*)Bs + rowb * 128 + chb * 16);
      }
      #pragma unroll
      for (int i = 0; i < 4; ++i)
        #pragma unroll
        for (int j = 0; j < 4; ++j)
          acc[i][j] = mfma16(aF[i], bF[j], acc[i][j]);
    }
    __syncthreads();
  }

  const int which = bn >> 2;
  __bf16* outp = (which == 0) ? q : (which == 1) ? k : v;
  const int ncolbase = bn * 128 + wn * 64 - which * 512;
  #pragma unroll
  for (int i = 0; i < 4; ++i) {
    #pragma unroll
    for (int r = 0; r < 4; ++r) {
      const int mrow = bm * 128 + wm * 64 + i * 16 + g * 4 + r;
      const float gt = (which == 0) ? gate[mrow] : 1.0f;
      #pragma unroll
      for (int j = 0; j < 4; ++j) {
        const int ncol = ncolbase + j * 16 + l15;
        float val = acc[i][j][r] + biasc[which * 512 + ncol];
        if (which == 0) val *= gt;
        outp[(size_t)mrow * 512 + ncol] = (__bf16)val;
      }
    }
  }
}

// ============ kernel 4: v [16384][512] -> vT [8][512][2048] ============
__global__ __launch_bounds__(256) void k_vtr(const __bf16* __restrict__ v,
                                             __bf16* __restrict__ vT) {
  __shared__ __bf16 tile[64][72];
  const int st = blockIdx.x, dt = blockIdx.y, b = blockIdx.z;
  const int t = threadIdx.x;
  {
    const int sl = t >> 2, dl = (t & 3) * 16;
    const __bf16* src = v + ((size_t)(b * 2048 + st * 64 + sl)) * 512 + dt * 64 + dl;
    *(bf16x8*)&tile[sl][dl]     = *(const bf16x8*)src;
    *(bf16x8*)&tile[sl][dl + 8] = *(const bf16x8*)(src + 8);
  }
  __syncthreads();
  {
    const int dl = t >> 2, sl = (t & 3) * 16;
    bf16x8 w0, w1;
    #pragma unroll
    for (int j = 0; j < 8; ++j) { w0[j] = tile[sl + j][dl]; w1[j] = tile[sl + 8 + j][dl]; }
    __bf16* dst = vT + ((size_t)(b * 512 + dt * 64 + dl)) * 2048 + st * 64 + sl;
    *(bf16x8*)dst = w0;
    *(bf16x8*)(dst + 8) = w1;
  }
}

// ============ kernel 5: S = exp(Q @ K^T), m97 128^2, NB batches ============
// grid NB*256. NB=8: id&7 = batch (XCD-pinned); NB=4: two XCDs per batch (R11 decode).
template<int NB>
__global__ __launch_bounds__(256, 3) void k_sexp(
    const __bf16* __restrict__ q, const __bf16* __restrict__ kg,
    __bf16* __restrict__ S) {
  __shared__ alignas(16) __bf16 As[8192];
  __shared__ alignas(16) __bf16 Bs[8192];
  const int id = blockIdx.x;
  int batch, t;
  if (NB == 8) { batch = id & 7;        t = id >> 3; }
  else         { batch = (id & 7) >> 1; t = ((id >> 3) << 1) | (id & 1); }
  const int mt = t & 15, nt = t >> 4;
  const int tid = threadIdx.x, w = tid >> 6, lane = tid & 63;
  const int g = lane >> 4, l15 = lane & 15;
  const int wm = w >> 1, wn = w & 1;
  f32x4 acc[4][4] = {};
  const char* Ab = (const char*)(q  + ((size_t)batch * 2048 + mt * 128) * 512);
  const char* Bb = (const char*)(kg + ((size_t)batch * 2048 + nt * 128) * 512);

  for (int kt = 0; kt < 8; ++kt) {
    const int k0b = kt * 128;
    #pragma unroll
    for (int i = 0; i < 4; ++i) {
      const int L = i * 4096 + w * 1024 + lane * 16;
      const int row = L >> 7;
      const int ch = (L >> 4) & 7;
      const int sch = ch ^ (row & 7);
      gload16(Ab + (size_t)row * 1024 + k0b + sch * 16, (char*)As + L);
      gload16(Bb + (size_t)row * 1024 + k0b + sch * 16, (char*)Bs + L);
    }
    __syncthreads();
    #pragma unroll
    for (int kk = 0; kk < 2; ++kk) {
      bf16x8 aF[4], bF[4];
      #pragma unroll
      for (int i = 0; i < 4; ++i) {
        const int rowa = wm * 64 + i * 16 + l15;
        const int cha = (kk * 4 + g) ^ (rowa & 7);
        aF[i] = *(const bf16x8*)((const char*)As + rowa * 128 + cha * 16);
        const int rowb = wn * 64 + i * 16 + l15;
        const int chb = (kk * 4 + g) ^ (rowb & 7);
        bF[i] = *(const bf16x8*)((const char*)Bs + rowb * 128 + chb * 16);
      }
      #pragma unroll
      for (int i = 0; i < 4; ++i)
        #pragma unroll
        for (int j = 0; j < 4; ++j)
          acc[i][j] = mfma16(aF[i], bF[j], acc[i][j]);
    }
    __syncthreads();
  }

  // epilogue: S = bf16(exp(acc))   (m = 0 softmax, validated R6-R12)
  __bf16* Srow = S + (size_t)batch * 2048 * 2048;
  #pragma unroll
  for (int i = 0; i < 4; ++i) {
    #pragma unroll
    for (int r = 0; r < 4; ++r) {
      const int mrow = mt * 128 + wm * 64 + i * 16 + g * 4 + r;
      #pragma unroll
      for (int j = 0; j < 4; ++j) {
        const int ncol = nt * 128 + wn * 64 + j * 16 + l15;
        Srow[(size_t)mrow * 2048 + ncol] = (__bf16)__expf(acc[i][j][r]);
      }
    }
  }
}

// ============ kernel 6: out = (S @ vT-rows) / (S @ 1), NB batches ============
// BM=64 BN=128 BK=64; grid NB*128. Swizzle: all 4 nt-blocks of an S panel
// (batch,mt) land on one XCD -> S re-reads are L2 hits.
template<int NB>
__global__ __launch_bounds__(256, 2) void k_pv(
    const __bf16* __restrict__ S, const __bf16* __restrict__ vT,
    float* __restrict__ out) {
  __shared__ alignas(16) __bf16 As[4096];    //  64 rows x 64 k = 8KB
  __shared__ alignas(16) __bf16 Bs[8192];    // 128 rows x 64 k = 16KB
  const int id = blockIdx.x;
  int p, nt;
  if (NB == 8) { const int h = id >> 3; nt = h >> 5; p = (h & 31) * 8 + (id & 7); }
  else         { const int h = id >> 3; nt = h >> 4; p = (h & 15) * 8 + (id & 7); }
  const int batch = p >> 5, mt = p & 31;
  const int tid = threadIdx.x, w = tid >> 6, lane = tid & 63;
  const int g = lane >> 4, l15 = lane & 15;
  const int wm = w >> 1, wn = w & 1;
  f32x4 acc[2][4] = {};
  f32x4 l_acc[2] = {};
  bf16x8 ones;
  #pragma unroll
  for (int j = 0; j < 8; ++j) ones[j] = (__bf16)1.0f;

  const char* Ab = (const char*)(S  + ((size_t)batch * 2048 + mt * 64) * 2048);
  const char* Bb = (const char*)(vT + ((size_t)batch * 512 + nt * 128) * 2048);

  for (int kt = 0; kt < 32; ++kt) {
    const int k0b = kt * 128;
    #pragma unroll
    for (int i = 0; i < 2; ++i) {
      const int L = i * 4096 + tid * 16;
      const int row = L >> 7, ch = (L >> 4) & 7, sch = ch ^ (row & 7);
      gload16(Ab + (size_t)row * 4096 + k0b + sch * 16, (char*)As + L);
    }
    #pragma unroll
    for (int i = 0; i < 4; ++i) {
      const int L = i * 4096 + tid * 16;
      const int row = L >> 7, ch = (L >> 4) & 7, sch = ch ^ (row & 7);
      gload16(Bb + (size_t)row * 4096 + k0b + sch * 16, (char*)Bs + L);
    }
    __syncthreads();
    #pragma unroll
    for (int kk = 0; kk < 2; ++kk) {
      bf16x8 aF[2], bF[4];
      #pragma unroll
      for (int i = 0; i < 2; ++i) {
        const int rowa = wm * 32 + i * 16 + l15;
        const int cha = (kk * 4 + g) ^ (rowa & 7);
        aF[i] = *(const bf16x8*)((const char*)As + rowa * 128 + cha * 16);
      }
      #pragma unroll
      for (int j = 0; j < 4; ++j) {
        const int rowb = wn * 64 + j * 16 + l15;
        const int chb = (kk * 4 + g) ^ (rowb & 7);
        bF[j] = *(const bf16x8*)((const char*)Bs + rowb * 128 + chb * 16);
      }
      #pragma unroll
      for (int i = 0; i < 2; ++i) {
        #pragma unroll
        for (int j = 0; j < 4; ++j)
          acc[i][j] = mfma16(aF[i], bF[j], acc[i][j]);
        l_acc[i] = mfma16(aF[i], ones, l_acc[i]);
      }
    }
    __syncthreads();
  }

  #pragma unroll
  for (int i = 0; i < 2; ++i) {
    #pragma unroll
    for (int r = 0; r < 4; ++r) {
      const size_t mrow = (size_t)batch * 2048 + mt * 64 + wm * 32 + i * 16 + g * 4 + r;
      const float inv = 1.0f / l_acc[i][r];
      #pragma unroll
      for (int j = 0; j < 4; ++j) {
        const int ncol = nt * 128 + wn * 64 + j * 16 + l15;
        out[mrow * 512 + ncol] = acc[i][j][r] * inv;
      }
    }
  }
}

// ============ launcher ============
extern "C" void kernel_launch(void* const* d_in, const int* in_sizes, int n_in,
                              void* d_out, int out_size, void* d_ws, size_t ws_size,
                              hipStream_t stream) {
  const float* tf  = (const float*)d_in[0];
  const float* env = (const float*)d_in[1];
  const float* Wq  = (const float*)d_in[2];
  const float* bq  = (const float*)d_in[3];
  const float* Wk  = (const float*)d_in[4];
  const float* bk  = (const float*)d_in[5];
  const float* Wv  = (const float*)d_in[6];
  const float* bv  = (const float*)d_in[7];
  const float* Wg  = (const float*)d_in[8];
  const float* bg  = (const float*)d_in[9];
  float* out = (float*)d_out;
  char* ws = (char*)d_ws;

  __bf16* xb   = (__bf16*)(ws + XB_OFF);
  __bf16* Sbuf = (__bf16*)(ws + S_OFF);
  __bf16* qb   = (__bf16*)(ws + Q_OFF);
  __bf16* kb   = (__bf16*)(ws + K_OFF);
  __bf16* vb   = (__bf16*)(ws + V_OFF);
  __bf16* vT   = (__bf16*)(ws + VT_OFF);
  __bf16* Wt   = (__bf16*)(ws + WT_OFF);
  float* biasc = (float*)(ws + BIAS_OFF);
  float* gate  = (float*)(ws + GATE_OFF);

  k_xbgate<<<dim3(16384), dim3(256), 0, stream>>>(tf, env, Wg, bg, xb, gate);
  k_wt<<<dim3(17, 8, 3), dim3(256), 0, stream>>>(Wq, Wk, Wv, bq, bk, bv, Wt, biasc);
  k_gemm<<<dim3(1536), dim3(256), 0, stream>>>(xb, Wt, biasc, gate, qb, kb, vb);
  k_vtr<<<dim3(32, 8, 8), dim3(256), 0, stream>>>(vb, vT);

  if (ws_size >= S8_OFF + 67108864UL) {
    // single pass over all 8 batches; S8 in dedicated region
    __bf16* S8 = (__bf16*)(ws + S8_OFF);
    k_sexp<8><<<dim3(2048), dim3(256), 0, stream>>>(qb, kb, S8);
    k_pv<8>  <<<dim3(1024), dim3(256), 0, stream>>>(S8, vT, out);
  } else {
    // two 4-batch groups; S reuses the dead xb region
    const size_t hb = 4UL * 2048 * 512;
    const size_t hv = 4UL * 512 * 2048;
    const size_t ho = 4UL * 2048 * 512;
    k_sexp<4><<<dim3(1024), dim3(256), 0, stream>>>(qb, kb, Sbuf);
    k_pv<4>  <<<dim3(512),  dim3(256), 0, stream>>>(Sbuf, vT, out);
    k_sexp<4><<<dim3(1024), dim3(256), 0, stream>>>(qb + hb, kb + hb, Sbuf);
    k_pv<4>  <<<dim3(512),  dim3(256), 0, stream>>>(Sbuf, vT + hv, out + ho);
  }
}

// Round 14
// 162.923 us; speedup vs baseline: 1.4693x; 1.1017x over previous
//
#include <hip/hip_runtime.h>
#include <stdint.h>

typedef __attribute__((ext_vector_type(8))) __bf16 bf16x8;
typedef __attribute__((ext_vector_type(4))) __bf16 bf16x4;
typedef __attribute__((ext_vector_type(4))) float  f32x4;

#define DEV __device__ __forceinline__

DEV void gload16(const void* g, void* l) {
  __builtin_amdgcn_global_load_lds((const __attribute__((address_space(1))) uint32_t*)g,
                                   (__attribute__((address_space(3))) uint32_t*)l,
                                   16, 0, 0);
}

DEV f32x4 mfma16(bf16x8 a, bf16x8 b, f32x4 c) {
  return __builtin_amdgcn_mfma_f32_16x16x32_bf16(a, b, c, 0, 0, 0);
}

// ---------------- workspace layout (bytes) ----------------
#define XB_OFF   0UL            // xbb: 16384 x 1024 bf16 = 33,554,432 ; reused as S (group mode)
#define S_OFF    0UL            // S (4-batch group): 33,554,432
#define Q_OFF    33554432UL     // 16384 x 512 bf16 = 16,777,216
#define K_OFF    50331648UL
#define VT_OFF   67108864UL     // [8][512][2048] bf16 = 16,777,216
#define WT_OFF   83886080UL     // 1536 x 1024 bf16 = 3,145,728
#define ENVQ_OFF 87031808UL     // 8 x 1536 f32 = 49,152
#define GATE_OFF 87080960UL     // 16384 f32 = 65,536
#define S8_OFF   87146496UL     // S (all 8 batches): 67,108,864 -> needs ws >= 154,255,360

// ============ kernel 1: xbb (bf16 cast of tf) + gate ============
__global__ __launch_bounds__(256) void k_xbgate(
    const float* __restrict__ tf, const float* __restrict__ env,
    const float* __restrict__ Wg, const float* __restrict__ bg,
    __bf16* __restrict__ xbb, float* __restrict__ gate) {
  const int row = blockIdx.x;     // 0..16383
  const int t   = threadIdx.x;    // 0..255
  const int b   = row >> 11;
  const float4 v  = ((const float4*)(tf + (size_t)row * 1024))[t];
  const float4 wv = ((const float4*)Wg)[t];
  float dot = v.x * wv.x + v.y * wv.y + v.z * wv.z + v.w * wv.w;
  bf16x4 o; o.x = (__bf16)v.x; o.y = (__bf16)v.y; o.z = (__bf16)v.z; o.w = (__bf16)v.w;
  *(bf16x4*)(xbb + (size_t)row * 1024 + t * 4) = o;
  if (t < 16) {
    const float4 e  = ((const float4*)(env + b * 64))[t];
    const float4 we = ((const float4*)Wg)[256 + t];
    dot += e.x * we.x + e.y * we.y + e.z * we.z + e.w * we.w;
  }
  #pragma unroll
  for (int m = 1; m < 64; m <<= 1) dot += __shfl_xor(dot, m, 64);
  __shared__ float red[4];
  if ((t & 63) == 0) red[t >> 6] = dot;
  __syncthreads();
  if (t == 0) {
    const float d = red[0] + red[1] + red[2] + red[3] + bg[0];
    gate[row] = 0.03125f / (1.0f + __expf(-d));   // sigmoid * 1/sqrt(1024)
  }
}

// ============ kernel 2: Wt[n][kk] = W[kk][n], kk < 1024 only ============
__global__ __launch_bounds__(256) void k_wt(
    const float* __restrict__ Wq, const float* __restrict__ Wk, const float* __restrict__ Wv,
    __bf16* __restrict__ Wt) {
  __shared__ float tile[64][65];
  const int kt = blockIdx.x;       // 0..15
  const int ct = blockIdx.y;       // 0..7
  const int which = blockIdx.z;    // 0=q 1=k 2=v
  const float* W = (which == 0) ? Wq : (which == 1) ? Wk : Wv;
  const int t = threadIdx.x;
  const int k0 = kt * 64, c0 = ct * 64;
  #pragma unroll
  for (int j = 0; j < 4; ++j) {
    const int rr = (t >> 4) + j * 16;
    const float4 v4 = *(const float4*)(W + (size_t)(k0 + rr) * 512 + c0 + (t & 15) * 4);
    tile[rr][(t & 15) * 4 + 0] = v4.x;
    tile[rr][(t & 15) * 4 + 1] = v4.y;
    tile[rr][(t & 15) * 4 + 2] = v4.z;
    tile[rr][(t & 15) * 4 + 3] = v4.w;
  }
  __syncthreads();
  #pragma unroll
  for (int j = 0; j < 4; ++j) {
    const int nl = (t >> 4) + j * 16;
    const int kl = (t & 15) * 4;
    bf16x4 o;
    o.x = (__bf16)tile[kl + 0][nl];
    o.y = (__bf16)tile[kl + 1][nl];
    o.z = (__bf16)tile[kl + 2][nl];
    o.w = (__bf16)tile[kl + 3][nl];
    *(bf16x4*)(Wt + (size_t)(which * 512 + c0 + nl) * 1024 + k0 + kl) = o;
  }
}

// ============ kernel 2b: envq[b][n] = bias[n] + env[b] . W[1024:1088][col] ============
// grid (6, 8): block = 256 consecutive n (never crosses a W boundary), coalesced W reads.
__global__ __launch_bounds__(256) void k_envq(
    const float* __restrict__ env,
    const float* __restrict__ Wq, const float* __restrict__ Wk, const float* __restrict__ Wv,
    const float* __restrict__ bq, const float* __restrict__ bk, const float* __restrict__ bv,
    float* __restrict__ envq) {
  const int n = blockIdx.x * 256 + threadIdx.x;   // 0..1535
  const int b = blockIdx.y;
  const int which = n >> 9, col = n & 511;
  const float* W    = (which == 0) ? Wq : (which == 1) ? Wk : Wv;
  const float* bias = (which == 0) ? bq : (which == 1) ? bk : bv;
  float s = bias[col];
  #pragma unroll 8
  for (int kk = 0; kk < 64; ++kk)
    s += env[b * 64 + kk] * W[(size_t)(1024 + kk) * 512 + col];
  envq[b * 1536 + n] = s;
}

// ============ kernel 3: QKV GEMM  M=16384 N=1536 K=1024 (m97 structure) ============
// v-blocks (bn>=8) add bias and write vT DIRECTLY via LDS XOR-swizzled transpose.
__global__ __launch_bounds__(256, 3) void k_gemm(
    const __bf16* __restrict__ xbb, const __bf16* __restrict__ Wt,
    const float* __restrict__ envq, const float* __restrict__ gate,
    __bf16* __restrict__ q, __bf16* __restrict__ k, __bf16* __restrict__ vT) {
  __shared__ alignas(16) __bf16 SM[16384];   // As | Bs ; reused as transpose tile
  __bf16* As = SM;
  __bf16* Bs = SM + 8192;
  const int id = blockIdx.x;
  const int xcd = id & 7, local = id >> 3;
  const int bm = xcd * 16 + (local & 15);
  const int bn = local >> 4;
  const int tid = threadIdx.x, w = tid >> 6, lane = tid & 63;
  const int g = lane >> 4, l15 = lane & 15;
  const int wm = w >> 1, wn = w & 1;
  f32x4 acc[4][4] = {};
  const char* Ab = (const char*)(xbb + (size_t)bm * 128 * 1024);
  const char* Bb = (const char*)(Wt + (size_t)bn * 128 * 1024);

  for (int kt = 0; kt < 16; ++kt) {
    const int k0b = kt * 128;
    #pragma unroll
    for (int i = 0; i < 4; ++i) {
      const int L = i * 4096 + w * 1024 + lane * 16;
      const int row = L >> 7;
      const int ch = (L >> 4) & 7;
      const int sch = ch ^ (row & 7);
      gload16(Ab + (size_t)row * 2048 + k0b + sch * 16, (char*)As + L);
      gload16(Bb + (size_t)row * 2048 + k0b + sch * 16, (char*)Bs + L);
    }
    __syncthreads();
    #pragma unroll
    for (int kk = 0; kk < 2; ++kk) {
      bf16x8 aF[4], bF[4];
      #pragma unroll
      for (int i = 0; i < 4; ++i) {
        const int rowa = wm * 64 + i * 16 + l15;
        const int cha = (kk * 4 + g) ^ (rowa & 7);
        aF[i] = *(const bf16x8*)((const char*)As + rowa * 128 + cha * 16);
        const int rowb = wn * 64 + i * 16 + l15;
        const int chb = (kk * 4 + g) ^ (rowb & 7);
        bF[i] = *(const bf16x8*)((const char*)Bs + rowb * 128 + chb * 16);
      }
      #pragma unroll
      for (int i = 0; i < 4; ++i)
        #pragma unroll
        for (int j = 0; j < 4; ++j)
          acc[i][j] = mfma16(aF[i], bF[j], acc[i][j]);
    }
    __syncthreads();
  }

  const int which = bn >> 2;          // 0=q 1=k 2=v (block-uniform)
  const int batch = bm >> 4;          // 128-row tiles never cross batch
  if (which < 2) {
    __bf16* outp = (which == 0) ? q : k;
    const int ncolbase = bn * 128 + wn * 64 - which * 512;
    #pragma unroll
    for (int i = 0; i < 4; ++i) {
      #pragma unroll
      for (int r = 0; r < 4; ++r) {
        const int mrow = bm * 128 + wm * 64 + i * 16 + g * 4 + r;
        const float gt = (which == 0) ? gate[mrow] : 1.0f;
        #pragma unroll
        for (int j = 0; j < 4; ++j) {
          const int ncol = ncolbase + j * 16 + l15;
          float val = acc[i][j][r] + envq[batch * 1536 + bn * 128 + wn * 64 + j * 16 + l15];
          if (which == 0) val *= gt;
          outp[(size_t)mrow * 512 + ncol] = (__bf16)val;
        }
      }
    }
  } else {
    // v-block: bias add + 128x128 LDS transpose (XOR swizzle, <=2-way banks) -> vT
    #pragma unroll
    for (int j = 0; j < 4; ++j) {
      const int ncol = wn * 64 + j * 16 + l15;                 // local dim 0..127
      const float bv = envq[batch * 1536 + bn * 128 + ncol];
      const int sw = (ncol & 7) << 3;
      #pragma unroll
      for (int i = 0; i < 4; ++i) {
        const int mbase = wm * 64 + i * 16 + g * 4;            // local key, 4-aligned
        bf16x4 pk;
        pk.x = (__bf16)(acc[i][j][0] + bv);
        pk.y = (__bf16)(acc[i][j][1] + bv);
        pk.z = (__bf16)(acc[i][j][2] + bv);
        pk.w = (__bf16)(acc[i][j][3] + bv);
        *(bf16x4*)(SM + ncol * 128 + (mbase ^ sw)) = pk;
      }
    }
    __syncthreads();
    const int colL = tid & 127, h = tid >> 7;
    const __bf16* src = SM + colL * 128;
    const int sw = (colL & 7) << 3;
    __bf16* dst = vT + ((size_t)batch * 512 + (bn - 8) * 128 + colL) * 2048
                     + (bm & 15) * 128 + h * 64;
    #pragma unroll
    for (int c = 0; c < 8; ++c) {
      const int m0 = h * 64 + c * 8;
      *(bf16x8*)(dst + c * 8) = *(const bf16x8*)(src + (m0 ^ sw));
    }
  }
}

// ============ kernel 5: S = exp(Q @ K^T), m97 128^2, NB batches ============
template<int NB>
__global__ __launch_bounds__(256, 3) void k_sexp(
    const __bf16* __restrict__ q, const __bf16* __restrict__ kg,
    __bf16* __restrict__ S) {
  __shared__ alignas(16) __bf16 As[8192];
  __shared__ alignas(16) __bf16 Bs[8192];
  const int id = blockIdx.x;
  int batch, t;
  if (NB == 8) { batch = id & 7;        t = id >> 3; }
  else         { batch = (id & 7) >> 1; t = ((id >> 3) << 1) | (id & 1); }
  const int mt = t & 15, nt = t >> 4;
  const int tid = threadIdx.x, w = tid >> 6, lane = tid & 63;
  const int g = lane >> 4, l15 = lane & 15;
  const int wm = w >> 1, wn = w & 1;
  f32x4 acc[4][4] = {};
  const char* Ab = (const char*)(q  + ((size_t)batch * 2048 + mt * 128) * 512);
  const char* Bb = (const char*)(kg + ((size_t)batch * 2048 + nt * 128) * 512);

  for (int kt = 0; kt < 8; ++kt) {
    const int k0b = kt * 128;
    #pragma unroll
    for (int i = 0; i < 4; ++i) {
      const int L = i * 4096 + w * 1024 + lane * 16;
      const int row = L >> 7;
      const int ch = (L >> 4) & 7;
      const int sch = ch ^ (row & 7);
      gload16(Ab + (size_t)row * 1024 + k0b + sch * 16, (char*)As + L);
      gload16(Bb + (size_t)row * 1024 + k0b + sch * 16, (char*)Bs + L);
    }
    __syncthreads();
    #pragma unroll
    for (int kk = 0; kk < 2; ++kk) {
      bf16x8 aF[4], bF[4];
      #pragma unroll
      for (int i = 0; i < 4; ++i) {
        const int rowa = wm * 64 + i * 16 + l15;
        const int cha = (kk * 4 + g) ^ (rowa & 7);
        aF[i] = *(const bf16x8*)((const char*)As + rowa * 128 + cha * 16);
        const int rowb = wn * 64 + i * 16 + l15;
        const int chb = (kk * 4 + g) ^ (rowb & 7);
        bF[i] = *(const bf16x8*)((const char*)Bs + rowb * 128 + chb * 16);
      }
      #pragma unroll
      for (int i = 0; i < 4; ++i)
        #pragma unroll
        for (int j = 0; j < 4; ++j)
          acc[i][j] = mfma16(aF[i], bF[j], acc[i][j]);
    }
    __syncthreads();
  }

  __bf16* Srow = S + (size_t)batch * 2048 * 2048;
  #pragma unroll
  for (int i = 0; i < 4; ++i) {
    #pragma unroll
    for (int r = 0; r < 4; ++r) {
      const int mrow = mt * 128 + wm * 64 + i * 16 + g * 4 + r;
      #pragma unroll
      for (int j = 0; j < 4; ++j) {
        const int ncol = nt * 128 + wn * 64 + j * 16 + l15;
        Srow[(size_t)mrow * 2048 + ncol] = (__bf16)__expf(acc[i][j][r]);
      }
    }
  }
}

// ============ kernel 6: out = (S @ vT-rows) / (S @ 1), m97 128^2 tile ============
// NB=8: grid 512, id&7=batch -> all nt-blocks of an S panel share an XCD.
template<int NB>
__global__ __launch_bounds__(256, 3) void k_pv(
    const __bf16* __restrict__ S, const __bf16* __restrict__ vT,
    float* __restrict__ out) {
  __shared__ alignas(16) __bf16 As[8192];
  __shared__ alignas(16) __bf16 Bs[8192];
  const int id = blockIdx.x;
  int batch, mt, nt;
  if (NB == 8) { batch = id & 7; const int h = id >> 3; mt = h & 15; nt = h >> 4; }
  else { batch = (id & 7) >> 1; const int h = ((id >> 3) << 1) | (id & 1); mt = h & 15; nt = h >> 4; }
  const int tid = threadIdx.x, w = tid >> 6, lane = tid & 63;
  const int g = lane >> 4, l15 = lane & 15;
  const int wm = w >> 1, wn = w & 1;
  f32x4 acc[4][4] = {};
  f32x4 l_acc[4] = {};
  bf16x8 ones;
  #pragma unroll
  for (int j = 0; j < 8; ++j) ones[j] = (__bf16)1.0f;

  const char* Ab = (const char*)(S  + ((size_t)batch * 2048 + mt * 128) * 2048);
  const char* Bb = (const char*)(vT + ((size_t)batch * 512 + nt * 128) * 2048);

  for (int kt = 0; kt < 32; ++kt) {
    const int k0b = kt * 128;
    #pragma unroll
    for (int i = 0; i < 4; ++i) {
      const int L = i * 4096 + w * 1024 + lane * 16;
      const int row = L >> 7, ch = (L >> 4) & 7, sch = ch ^ (row & 7);
      gload16(Ab + (size_t)row * 4096 + k0b + sch * 16, (char*)As + L);
      gload16(Bb + (size_t)row * 4096 + k0b + sch * 16, (char*)Bs + L);
    }
    __syncthreads();
    #pragma unroll
    for (int kk = 0; kk < 2; ++kk) {
      bf16x8 aF[4], bF[4];
      #pragma unroll
      for (int i = 0; i < 4; ++i) {
        const int rowa = wm * 64 + i * 16 + l15;
        const int cha = (kk * 4 + g) ^ (rowa & 7);
        aF[i] = *(const bf16x8*)((const char*)As + rowa * 128 + cha * 16);
        const int rowb = wn * 64 + i * 16 + l15;
        const int chb = (kk * 4 + g) ^ (rowb & 7);
        bF[i] = *(const bf16x8*)((const char*)Bs + rowb * 128 + chb * 16);
      }
      #pragma unroll
      for (int i = 0; i < 4; ++i) {
        #pragma unroll
        for (int j = 0; j < 4; ++j)
          acc[i][j] = mfma16(aF[i], bF[j], acc[i][j]);
        l_acc[i] = mfma16(aF[i], ones, l_acc[i]);
      }
    }
    __syncthreads();
  }

  #pragma unroll
  for (int i = 0; i < 4; ++i) {
    #pragma unroll
    for (int r = 0; r < 4; ++r) {
      const size_t mrow = (size_t)batch * 2048 + mt * 128 + wm * 64 + i * 16 + g * 4 + r;
      const float inv = 1.0f / l_acc[i][r];
      #pragma unroll
      for (int j = 0; j < 4; ++j) {
        const int ncol = nt * 128 + wn * 64 + j * 16 + l15;
        out[mrow * 512 + ncol] = acc[i][j][r] * inv;
      }
    }
  }
}

// ============ launcher ============
extern "C" void kernel_launch(void* const* d_in, const int* in_sizes, int n_in,
                              void* d_out, int out_size, void* d_ws, size_t ws_size,
                              hipStream_t stream) {
  const float* tf  = (const float*)d_in[0];
  const float* env = (const float*)d_in[1];
  const float* Wq  = (const float*)d_in[2];
  const float* bq  = (const float*)d_in[3];
  const float* Wk  = (const float*)d_in[4];
  const float* bk  = (const float*)d_in[5];
  const float* Wv  = (const float*)d_in[6];
  const float* bv  = (const float*)d_in[7];
  const float* Wg  = (const float*)d_in[8];
  const float* bg  = (const float*)d_in[9];
  float* out = (float*)d_out;
  char* ws = (char*)d_ws;

  __bf16* xbb  = (__bf16*)(ws + XB_OFF);
  __bf16* Sbuf = (__bf16*)(ws + S_OFF);
  __bf16* qb   = (__bf16*)(ws + Q_OFF);
  __bf16* kb   = (__bf16*)(ws + K_OFF);
  __bf16* vT   = (__bf16*)(ws + VT_OFF);
  __bf16* Wt   = (__bf16*)(ws + WT_OFF);
  float* envq  = (float*)(ws + ENVQ_OFF);
  float* gate  = (float*)(ws + GATE_OFF);

  k_xbgate<<<dim3(16384), dim3(256), 0, stream>>>(tf, env, Wg, bg, xbb, gate);
  k_wt<<<dim3(16, 8, 3), dim3(256), 0, stream>>>(Wq, Wk, Wv, Wt);
  k_envq<<<dim3(6, 8), dim3(256), 0, stream>>>(env, Wq, Wk, Wv, bq, bk, bv, envq);
  k_gemm<<<dim3(1536), dim3(256), 0, stream>>>(xbb, Wt, envq, gate, qb, kb, vT);

  if (ws_size >= S8_OFF + 67108864UL) {
    __bf16* S8 = (__bf16*)(ws + S8_OFF);
    k_sexp<8><<<dim3(2048), dim3(256), 0, stream>>>(qb, kb, S8);
    k_pv<8>  <<<dim3(512),  dim3(256), 0, stream>>>(S8, vT, out);
  } else {
    const size_t hb = 4UL * 2048 * 512;
    const size_t hv = 4UL * 512 * 2048;
    const size_t ho = 4UL * 2048 * 512;
    k_sexp<4><<<dim3(1024), dim3(256), 0, stream>>>(qb, kb, Sbuf);
    k_pv<4>  <<<dim3(256),  dim3(256), 0, stream>>>(Sbuf, vT, out);
    k_sexp<4><<<dim3(1024), dim3(256), 0, stream>>>(qb + hb, kb + hb, Sbuf);
    k_pv<4>  <<<dim3(256),  dim3(256), 0, stream>>>(Sbuf, vT + hv, out + ho);
  }
}